// Round 5
// baseline (395.328 us; speedup 1.0000x reference)
//
#include <hip/hip_runtime.h>
#include <stdint.h>

// BinaryDense: out[8192,4096] = x[8192,4096] @ sign(kernel[4096,4096]) + bias[4096]
// R8: fragment-major layout. R6/R7 both measured EXACTLY 12.58M LDS bank-conflict
// cycles (= 4.0 cyc per ds_read_b128, invariant across two swizzles) and LDS port
// occupancy ~90-115k cyc/block vs MFMA 75k -> LDS is the binding resource.
// Fix: store Xq/Wq in GLOBAL memory in MFMA-fragment order:
//   addr(band,t,c,r31) = band*131072 + t*2048 + c*512 + r31*16
//   (band = row/32, t = k-tile of 64, c = 16B-chunk, r31 = row%32)
// GEMM staging then reads 1024 contiguous B per wave gload_lds (linear src AND
// linear LDS dest -> rule 21 trivially satisfied, no swizzle), and every frag
// ds_read_b128 is wave-uniform-base + lane*16 -> conflict-free by construction.
// Data->lane mapping identical to R7 (row=m0+grp*32+(l&31), kbytes=(2kk+hi)*16);
// only LDS slot positions changed. Pipeline = R7's 4-buffer counted-vmcnt:
//   tile t (P=t&3, Q=(t+1)&3, S=(t+2)&3):
//     s1: rd(P,kk1)->Y ; stage(t+2 -> S) ; MM(X) ; vmcnt(4) ; barrier
//     s2: rd(Q,kk0)->X ; MM(Y)
// Prep: quant (row-major Xq) -> fused {sign(w)->Wq fragment-major; in-place
// band-local permutation of Xq (regs -> barrier -> writes; band-local, no
// cross-block hazard; ws footprint unchanged)}.

typedef int int4v __attribute__((ext_vector_type(4)));
typedef int int16v __attribute__((ext_vector_type(16)));

constexpr int M = 8192, N = 4096, K = 4096;
constexpr int BM = 256, BN = 256, BK = 64;  // i8 elements (= bytes)
constexpr int NT = K / BK;                  // 64 K-tiles
constexpr int BANDSZ = 131072;              // 32 rows * 4096 k bytes

__device__ __forceinline__ void gload_lds16(const void* g, void* l) {
  __builtin_amdgcn_global_load_lds(
      (const __attribute__((address_space(1))) unsigned int*)g,
      (__attribute__((address_space(3))) unsigned int*)l, 16, 0, 0);
}

#define FENCE asm volatile("" ::: "memory")

// ---- kernel 1: per-row absmax quantize x -> i8 (row-major Xq); rscale ----
__global__ __launch_bounds__(256) void quant_x_kernel(const float* __restrict__ x,
                                                      signed char* __restrict__ xq,
                                                      float* __restrict__ rscale) {
  const int row = blockIdx.x;
  const int t = threadIdx.x;
  const float* xr = x + (size_t)row * K;
  float4 v[4];
  float mx = 0.f;
#pragma unroll
  for (int i = 0; i < 4; ++i) {
    v[i] = *(const float4*)(xr + t * 16 + i * 4);
    mx = fmaxf(mx, fmaxf(fmaxf(fabsf(v[i].x), fabsf(v[i].y)),
                         fmaxf(fabsf(v[i].z), fabsf(v[i].w))));
  }
#pragma unroll
  for (int off = 32; off >= 1; off >>= 1)
    mx = fmaxf(mx, __shfl_xor(mx, off, 64));
  __shared__ float smax[4];
  if ((t & 63) == 0) smax[t >> 6] = mx;
  __syncthreads();
  const float rm = fmaxf(fmaxf(smax[0], smax[1]), fmaxf(smax[2], smax[3]));
  const float s = (rm > 0.f) ? 127.f / rm : 0.f;
  if (t == 0) rscale[row] = (rm > 0.f) ? rm / 127.f : 0.f;
  uint32_t o[4];
#pragma unroll
  for (int i = 0; i < 4; ++i) {
    float f[4] = {v[i].x, v[i].y, v[i].z, v[i].w};
    uint32_t p = 0;
#pragma unroll
    for (int j = 0; j < 4; ++j) {
      int q = (int)rintf(f[j] * s);  // in [-127,127] by construction
      p |= ((uint32_t)(uint8_t)(signed char)q) << (8 * j);
    }
    o[i] = p;
  }
  *(int4v*)(xq + (size_t)row * K + t * 16) = (int4v){(int)o[0], (int)o[1], (int)o[2], (int)o[3]};
}

// ---- kernel 2: fused. blocks [0,4096): sign(w)^T -> Wq fragment-major.
//      blocks [4096,4352): in-place band-local relayout of Xq to fragment-major.
__global__ __launch_bounds__(256) void prep2_kernel(const float* __restrict__ w,
                                                    signed char* __restrict__ wq,
                                                    signed char* __restrict__ xq) {
  const int t = threadIdx.x;
  if (blockIdx.x < 4096) {
    // sign-transpose one 64(n) x 64(k) tile of w.
    __shared__ __align__(16) signed char tile[64 * 68];  // pad 68
    const int idx = blockIdx.x;
    const int n0 = (idx & 63) * 64, k0 = (idx >> 6) * 64;
#pragma unroll
    for (int i = 0; i < 4; ++i) {
      int kl = (t >> 4) + i * 16;  // 0..63
      int nl = (t & 15) * 4;       // 0..60
      float4 v = *(const float4*)(w + (size_t)(k0 + kl) * N + n0 + nl);
      uint32_t p = 0;
      p |= ((uint32_t)(uint8_t)(signed char)((v.x > 0.f) - (v.x < 0.f)));
      p |= ((uint32_t)(uint8_t)(signed char)((v.y > 0.f) - (v.y < 0.f))) << 8;
      p |= ((uint32_t)(uint8_t)(signed char)((v.z > 0.f) - (v.z < 0.f))) << 16;
      p |= ((uint32_t)(uint8_t)(signed char)((v.w > 0.f) - (v.w < 0.f))) << 24;
      *(uint32_t*)(tile + kl * 68 + nl) = p;
    }
    __syncthreads();
    const int nl = t >> 2;      // 0..63
    const int ci = t & 3;       // chunk within tile: kc = ci*16
    uint32_t o[4] = {0, 0, 0, 0};
#pragma unroll
    for (int j = 0; j < 16; ++j)
      o[j >> 2] |= ((uint32_t)(uint8_t)tile[(ci * 16 + j) * 68 + nl]) << (8 * (j & 3));
    const int n = n0 + nl;
    const int nband = n >> 5, n31 = n & 31;
    const int tt = k0 >> 6;
    *(int4v*)(wq + (size_t)nband * BANDSZ + tt * 2048 + ci * 512 + n31 * 16) =
        (int4v){(int)o[0], (int)o[1], (int)o[2], (int)o[3]};
  } else {
    // in-place permutation of one 32-row band of Xq:
    //   new[band*131072 + (t*4+c)*512 + r31*16] = old[band*131072 + r31*4096 + t*64 + c*16]
    const int band = blockIdx.x - 4096;  // 0..255
    signed char* base = xq + (size_t)band * BANDSZ;
    const int r31 = t & 31, cp = t >> 5;  // cp 0..7
    int4v v[32];
#pragma unroll
    for (int g = 0; g < 32; ++g) {
      const int idx = g * 8 + cp;        // (tile,chunk) id 0..255
      v[g] = *(const int4v*)(base + r31 * 4096 + (idx >> 2) * 64 + (idx & 3) * 16);
    }
    __syncthreads();  // all reads landed (vmcnt(0) before barrier) before any write
#pragma unroll
    for (int g = 0; g < 32; ++g) {
      const int idx = g * 8 + cp;
      *(int4v*)(base + idx * 512 + r31 * 16) = v[g];
    }
  }
}

// ---- kernel 3: i8 32x32x32 MFMA GEMM, fragment-major LDS, 4-buf pipeline ----
// LDS buf p (32KB): A units at p*32768 + u*1024, B units at +16384 + u*1024;
// unit u = (grp*2+kk), lane offset = lane*16. All reads/writes lane-linear.

#define RD_SET(AN, BN_, P, KK)                                                 \
  {                                                                            \
    _Pragma("unroll") for (int mi_ = 0; mi_ < 4; ++mi_) {                      \
      AN[mi_] = *(const int4v*)(smem + (P)*32768 + wm * 8192 + mi_ * 2048 +    \
                                (KK)*1024 + lane16);                           \
    }                                                                          \
    _Pragma("unroll") for (int ni_ = 0; ni_ < 2; ++ni_) {                      \
      BN_[ni_] = *(const int4v*)(smem + (P)*32768 + 16384 + wn * 4096 +        \
                                 ni_ * 2048 + (KK)*1024 + lane16);             \
    }                                                                          \
  }

#define MM(AN, BN_)                                                            \
  {                                                                            \
    __builtin_amdgcn_s_setprio(1);                                             \
    _Pragma("unroll") for (int mi_ = 0; mi_ < 4; ++mi_) {                      \
      _Pragma("unroll") for (int ni_ = 0; ni_ < 2; ++ni_) {                    \
        acc[mi_][ni_] = __builtin_amdgcn_mfma_i32_32x32x32_i8(                 \
            AN[mi_], BN_[ni_], acc[mi_][ni_], 0, 0, 0);                        \
      }                                                                        \
    }                                                                          \
    __builtin_amdgcn_s_setprio(0);                                             \
  }

// one tile: P = T&3, Q = (T+1)&3, S = (T+2)&3 (compile-time buf constants).
#define TILE(P, Q, S, T)                                                       \
  {                                                                            \
    RD_SET(aY, bY, P, 1);                                                      \
    const bool more2_ = (T) + 2 < NT;                                          \
    if (more2_) stage(S, (T) + 2);                                             \
    MM(aX, bX);                                                                \
    if (more2_) {                                                              \
      asm volatile("s_waitcnt vmcnt(4)" ::: "memory");                         \
    } else {                                                                   \
      asm volatile("s_waitcnt vmcnt(0)" ::: "memory");                         \
    }                                                                          \
    __builtin_amdgcn_s_barrier();                                              \
    FENCE;                                                                     \
    if ((T) + 1 < NT) RD_SET(aX, bX, Q, 0);                                    \
    MM(aY, bY);                                                                \
    FENCE;                                                                     \
  }

__global__ __launch_bounds__(512, 2) void gemm_bin_kernel(
    const signed char* __restrict__ Xq,
    const signed char* __restrict__ Wq,
    const float* __restrict__ rscale,
    const float* __restrict__ bias,
    float* __restrict__ out) {
  __shared__ __align__(16) signed char smem[131072];

  const int tid = threadIdx.x;
  const int w = tid >> 6;
  const int lane = tid & 63;
  const int wm = w >> 2;     // 0..1 -> rows wm*128
  const int wn = w & 3;      // 0..3 -> cols wn*64
  const int hi = lane >> 5;  // k-half within 32-k step
  const int l31 = lane & 31;
  const int lane16 = lane * 16;
  const size_t m0 = (size_t)blockIdx.y * BM;
  const size_t n0 = (size_t)blockIdx.x * BN;

  int16v acc[4][2];
#pragma unroll
  for (int i = 0; i < 4; ++i)
#pragma unroll
    for (int j = 0; j < 2; ++j)
#pragma unroll
      for (int r = 0; r < 16; ++r) acc[i][j][r] = 0;
  int4v aX[4], bX[2], aY[4], bY[2];  // ping-pong operand sets

  // stage one 32KB K-tile: A (2 loads/thread) + B (2 loads/thread).
  // src is 1024B-contiguous per wave-load; dest = base + pos*16 linear.
  const size_t abase0 = (m0 >> 5) * (size_t)BANDSZ;
  const size_t bbase0 = (n0 >> 5) * (size_t)BANDSZ;
  auto stage = [&](int pb, int t) {
    signed char* lb = smem + pb * 32768;
    const size_t at = abase0 + (size_t)t * 2048;
    const size_t bt = bbase0 + (size_t)t * 2048;
#pragma unroll
    for (int it = 0; it < 2; ++it) {
      int pos = it * 512 + tid;
      gload_lds16(Xq + at + (size_t)(pos >> 7) * BANDSZ + ((pos >> 6) & 1) * 1024 +
                      (pos & 63) * 16,
                  lb + pos * 16);
    }
#pragma unroll
    for (int it = 0; it < 2; ++it) {
      int pos = it * 512 + tid;
      gload_lds16(Wq + bt + (size_t)(pos >> 7) * BANDSZ + ((pos >> 6) & 1) * 1024 +
                      (pos & 63) * 16,
                  lb + 16384 + pos * 16);
    }
  };

  // prologue: stage tiles 0,1; drain tile 0 (counted); first operands.
  stage(0, 0);
  stage(1, 1);
  asm volatile("s_waitcnt vmcnt(4)" ::: "memory");
  __builtin_amdgcn_s_barrier();
  FENCE;
  RD_SET(aX, bX, 0, 0);

#pragma unroll 1
  for (int t = 0; t < NT; t += 4) {
    TILE(0, 1, 2, t)
    TILE(1, 2, 3, t + 1)
    TILE(2, 3, 0, t + 2)
    TILE(3, 0, 1, t + 3)
  }

  // epilogue: 32x32 C/D layout: col=lane&31, row=(reg&3)+8*(reg>>2)+4*(lane>>5)
#pragma unroll
  for (int mi = 0; mi < 4; ++mi) {
    const size_t rbase = m0 + wm * 128 + mi * 32;
    float sc[4][4];  // [quad q][elem j]: row = rbase + hi*4 + q*8 + j
#pragma unroll
    for (int q = 0; q < 4; ++q)
      *(float4*)sc[q] = *(const float4*)(rscale + rbase + hi * 4 + q * 8);
#pragma unroll
    for (int ni = 0; ni < 2; ++ni) {
      const size_t col = n0 + wn * 64 + ni * 32 + l31;
      const float bv = bias[col];
#pragma unroll
      for (int r = 0; r < 16; ++r) {
        const int row = (r & 3) + 8 * (r >> 2) + 4 * hi;
        out[(rbase + row) * N + col] = (float)acc[mi][ni][r] * sc[r >> 2][r & 3] + bv;
      }
    }
  }
}

extern "C" void kernel_launch(void* const* d_in, const int* in_sizes, int n_in,
                              void* d_out, int out_size, void* d_ws, size_t ws_size,
                              hipStream_t stream) {
  const float* x = (const float*)d_in[0];
  const float* kern = (const float*)d_in[1];
  const float* bias = (const float*)d_in[2];
  float* out = (float*)d_out;

  signed char* Xq = (signed char*)d_ws;                 // 32 MiB (relaid in place)
  signed char* Wq = Xq + (size_t)M * K;                 // 16 MiB
  float* rscale = (float*)(Wq + (size_t)N * K);         // 32 KiB

  quant_x_kernel<<<M, 256, 0, stream>>>(x, Xq, rscale);
  prep2_kernel<<<4096 + 256, 256, 0, stream>>>(kern, Wq, Xq);
  gemm_bin_kernel<<<dim3(N / BN, M / BM), 512, 0, stream>>>(Xq, Wq, rscale, bias, out);
}